// Round 1
// baseline (1411.715 us; speedup 1.0000x reference)
//
#include <hip/hip_runtime.h>
#include <math.h>

// ---------------- problem constants ----------------
#define T_LEN   2880000      // samples per channel
#define NFFT    2048
#define HOP     512
#define LASTFR  5625         // frames are t = 0..5625 (5626 frames)
#define KCH     9            // 512-sample output chunks per EQ block
#define NBLK_EQ 625          // 625 * 9 * 512 = 2,880,000
#define SCAN_B  7680         // scan block size (375 blocks/channel)
#define SCAN_L  30720        // scan warm-up (contraction e^-6.4)

__device__ __forceinline__ float2 cmulf(float2 a, float2 b) {
    return make_float2(a.x * b.x - a.y * b.y, a.x * b.y + a.y * b.x);
}

// ---- 11-stage radix-2 Stockham (DIF, natural in -> natural out). ----
// Input in xin, result lands in yin (odd stage count). Verified by hand on N=4.
__device__ void fft_stages(float2* xin, float2* yin, const float2* __restrict__ TW) {
    float2* x = xin;
    float2* y = yin;
    int s = 1;
    #pragma unroll 1
    for (int st = 0; st < 11; ++st) {
        const int tid = threadIdx.x;
        #pragma unroll
        for (int r = 0; r < 4; ++r) {
            int i  = tid + (r << 8);        // butterfly index in [0,1024)
            int hi = i & ~(s - 1);          // = p*s, twiddle index W_2048^{p*s}
            float2 a = x[i];
            float2 b = x[i + 1024];
            float2 w = TW[hi];
            float2 sum = make_float2(a.x + b.x, a.y + b.y);
            float2 dif = make_float2(a.x - b.x, a.y - b.y);
            y[i + hi]     = sum;
            y[i + hi + s] = cmulf(dif, w);
        }
        __syncthreads();
        float2* t = x; x = y; y = t;
        s <<= 1;
    }
}

// emit one finished 512-sample chunk (slots r0,r1) with wsum normalization
__device__ __forceinline__ void emit_chunk(float* __restrict__ dst, const float* __restrict__ WN,
                                           int cchunk, int tid, float2 r0, float2 r1) {
    #pragma unroll
    for (int q = 0; q < 2; ++q) {
        float2 rr = (q == 0) ? r0 : r1;
        int m = cchunk * 512 + (q << 8) + tid;            // padded-signal coord
        int tmn = (m >= 2048) ? (((m - 2048) >> 9) + 1) : 0;
        int tmx = min(LASTFR, m >> 9);
        float wsum = 0.0f;
        for (int tt = tmn; tt <= tmx; ++tt) {
            float w = WN[m - (tt << 9)];
            wsum += w * w;
        }
        float inv = (wsum > 1e-11f) ? (1.0f / wsum) : 1.0f;
        int o = m - 1024;                                  // crop reflect pad
        dst[o]         = rr.x * inv;
        dst[T_LEN + o] = rr.y * inv;
    }
}

// One EQ band: STFT -> real-even mask -> ISTFT with OLA/wsum, exact reference replication.
// Both channels packed as one complex signal (mask real => channels stay separated).
__global__ __launch_bounds__(256) void eq_band_kernel(
    const float* __restrict__ src, float* __restrict__ dst,
    const float* __restrict__ gain_db_p, const float f0)
{
    __shared__ float2 SA[2048];   // 16 KB
    __shared__ float2 SB[2048];   // 16 KB
    __shared__ float2 TW[1024];   // 8 KB
    __shared__ float  MK[1025];   // mask/2048
    __shared__ float  WN[2048];   // hann
    // total ~53 KB -> 3 blocks/CU

    const int tid = threadIdx.x;
    const int b   = blockIdx.x;

    const float gdb   = *gain_db_p;
    const float g_lin = exp2f(gdb * 0.16609640474436813f);  // 10^(g/20)
    const float gm1   = g_lin - 1.0f;

    for (int k = tid; k < 1025; k += 256) {
        float f = (float)k * (24000.0f / 1024.0f);
        float d = (f - f0) / f0;                 // q = 1
        MK[k] = (1.0f + gm1 * expf(-d * d)) * (1.0f / 2048.0f);  // 1/N folded in
    }
    const float step = 6.283185307179586f / 2048.0f;
    for (int j = tid; j < 2048; j += 256)
        WN[j] = 0.5f - 0.5f * cosf((float)j * step);
    for (int k = tid; k < 1024; k += 256) {
        float ang = (float)k * step;
        TW[k] = make_float2(cosf(ang), -sinf(ang));          // W_2048^k
    }
    __syncthreads();

    const int t0   = max(0, 9 * b - 1);
    const int t1   = min(LASTFR, 9 * b + 10);
    const int cmin = 9 * b + 2;     // first output chunk (padded coords)
    const int cmax = 9 * b + 10;    // last output chunk

    // OLA ring: slot q holds sample m = t*512 + 256*q + tid at frame t's turn
    float2 ring[8];
    #pragma unroll
    for (int q = 0; q < 8; ++q) ring[q] = make_float2(0.0f, 0.0f);

    for (int t = t0; t <= t1; ++t) {
        // load windowed frame, reflect padding folded into index
        for (int j = tid; j < 2048; j += 256) {
            int ss = t * 512 + j - 1024;
            ss = (ss < 0) ? -ss : ss;
            ss = (ss >= T_LEN) ? (2 * T_LEN - 2 - ss) : ss;
            float w = WN[j];
            SA[j] = make_float2(src[ss] * w, src[T_LEN + ss] * w);
        }
        __syncthreads();

        fft_stages(SA, SB, TW);                  // forward, result in SB

        // Z = conj(F) * M/N   (ifft via conj trick; M real-even)
        for (int k = tid; k < 2048; k += 256) {
            float2 v = SB[k];
            float mk = MK[(k <= 1024) ? k : (2048 - k)];
            SB[k] = make_float2(v.x * mk, -(v.y * mk));
        }
        __syncthreads();

        fft_stages(SB, SA, TW);                  // "inverse", result in SA
        // SA[j] = conj(y0 + i*y1): ch0 = Re, ch1 = -Im ; apply synthesis window
        #pragma unroll
        for (int q = 0; q < 8; ++q) {
            int j = tid + (q << 8);
            float2 v = SA[j];
            float w  = WN[j];
            ring[q].x += v.x * w;
            ring[q].y -= v.y * w;
        }
        __syncthreads();                         // SA reusable next frame

        if (t >= cmin)                           // chunk t is complete now
            emit_chunk(dst, WN, t, tid, ring[0], ring[1]);

        #pragma unroll
        for (int q = 0; q < 6; ++q) ring[q] = ring[q + 2];
        ring[6] = make_float2(0.0f, 0.0f);
        ring[7] = make_float2(0.0f, 0.0f);
    }
    // tail (only last block: t1 clamped to 5625 < cmax)
    for (int c = t1 + 1; c <= cmax; ++c) {
        emit_chunk(dst, WN, c, tid, ring[0], ring[1]);
        #pragma unroll
        for (int q = 0; q < 6; ++q) ring[q] = ring[q + 2];
        ring[6] = make_float2(0.0f, 0.0f);
        ring[7] = make_float2(0.0f, 0.0f);
    }
}

// per-sample gain-reduction * a_att (gr[0] of each channel zeroed => exact i=0 boundary)
__global__ __launch_bounds__(256) void gr_kernel(
    const float* __restrict__ y, float* __restrict__ ga,
    const float* __restrict__ thr_p, const float* __restrict__ ratio_p,
    const float* __restrict__ att_p)
{
    int i = blockIdx.x * 256 + threadIdx.x;
    if (i >= 2 * T_LEN) return;
    float thr   = *thr_p;
    float ratio = *ratio_p;
    float a_att = 1.0f - expf(-1.0f / ((*att_p) * 48000.0f));
    float v  = y[i];
    float aa = fabsf(v) + 1e-8f;
    float adb = 6.020599913279624f * __log2f(aa);          // 20*log10
    float gr  = fmaxf(adb - thr, 0.0f) * (1.0f - 1.0f / ratio);
    float gav = gr * a_att;
    if (i == 0 || i == T_LEN) gav = 0.0f;
    ga[i] = gav;
}

// one scan-proc: 16 sequential IIR updates + prefetch 128 samples ahead
__device__ __forceinline__ void scan_proc(const float* __restrict__ g, float* __restrict__ out,
                                          float4 (&row)[4], int& i, float& prev,
                                          float A, float B, float ra, bool store)
{
    float4 a0 = row[0], a1 = row[1], a2 = row[2], a3 = row[3];
    int pf = i + 128;
    pf = (pf > T_LEN - 16) ? (T_LEN - 16) : pf;
    row[0] = *(const float4*)(g + pf);
    row[1] = *(const float4*)(g + pf + 4);
    row[2] = *(const float4*)(g + pf + 8);
    row[3] = *(const float4*)(g + pf + 12);
    float v[16] = {a0.x, a0.y, a0.z, a0.w, a1.x, a1.y, a1.z, a1.w,
                   a2.x, a2.y, a2.z, a2.w, a3.x, a3.y, a3.z, a3.w};
    float ov[16];
    #pragma unroll
    for (int k = 0; k < 16; ++k) {
        // new = max((1-a_att)p + a_att*g, (1-a_rel)p + a_rel*g)  == reference step
        prev = fmaxf(fmaf(A, prev, v[k]), fmaf(B, prev, v[k] * ra));
        ov[k] = prev;
    }
    if (store) {
        *(float4*)(out + i)      = make_float4(ov[0], ov[1], ov[2], ov[3]);
        *(float4*)(out + i + 4)  = make_float4(ov[4], ov[5], ov[6], ov[7]);
        *(float4*)(out + i + 8)  = make_float4(ov[8], ov[9], ov[10], ov[11]);
        *(float4*)(out + i + 12) = make_float4(ov[12], ov[13], ov[14], ov[15]);
    }
    i += 16;
}

// block-parallel IIR gain smoothing with warm-up (contraction bound)
__global__ __launch_bounds__(64) void scan_kernel(
    const float* __restrict__ ga, float* __restrict__ gs,
    const float* __restrict__ att_p, const float* __restrict__ rel_p)
{
    int gid = blockIdx.x * 64 + threadIdx.x;
    if (gid >= 750) return;                    // 375 blocks x 2 channels
    int c   = gid / 375;
    int blk = gid - c * 375;
    const float* __restrict__ g  = ga + c * T_LEN;
    float* __restrict__ out      = gs + c * T_LEN;

    float A  = expf(-1.0f / ((*att_p) * 48000.0f));   // 1 - a_att
    float B  = expf(-1.0f / ((*rel_p) * 48000.0f));   // 1 - a_rel
    float ra = (1.0f - B) / (1.0f - A);               // a_rel / a_att

    int o0     = blk * SCAN_B;
    int wstart = max(0, o0 - SCAN_L);                 // multiple of 16; blocks 0..4 exact
    int warm_groups = (o0 - wstart) >> 7;             // 128 samples per group

    float4 rb[8][4];                                  // 8-line (128-sample) prefetch ring
    #pragma unroll
    for (int l = 0; l < 8; ++l) {
        int idx = wstart + (l << 4);
        #pragma unroll
        for (int q = 0; q < 4; ++q)
            rb[l][q] = *(const float4*)(g + idx + (q << 2));
    }
    float prev = 0.0f;
    int i = wstart;

    for (int grp = 0; grp < warm_groups; ++grp) {
        #pragma unroll
        for (int ph = 0; ph < 8; ++ph)
            scan_proc(g, out, rb[ph], i, prev, A, B, ra, false);
    }
    for (int grp = 0; grp < 60; ++grp) {              // 60*128 = 7680 outputs
        #pragma unroll
        for (int ph = 0; ph < 8; ++ph)
            scan_proc(g, out, rb[ph], i, prev, A, B, ra, true);
    }
}

// makeup/gain application + saturation; gs read from io and overwritten in place
__global__ __launch_bounds__(256) void final_kernel(
    const float* __restrict__ y, float* __restrict__ io,
    const float* __restrict__ mk_p, const float* __restrict__ sat_p)
{
    int i = blockIdx.x * 256 + threadIdx.x;
    if (i >= 2 * T_LEN) return;
    float mk  = *mk_p;
    float sat = *sat_p;
    float v   = y[i];
    float gsv = io[i];
    float aa  = fabsf(v) + 1e-8f;
    float gl  = exp2f((mk - gsv) * 0.16609640474436813f);  // 10^((mk-gs)/20)
    float r   = aa * gl;
    r = (v < 0.0f) ? -r : r;
    if (sat > 1.0f) r = tanhf(r * sat) / sat;
    io[i] = r;
}

extern "C" void kernel_launch(void* const* d_in, const int* in_sizes, int n_in,
                              void* d_out, int out_size, void* d_ws, size_t ws_size,
                              hipStream_t stream)
{
    const float* audio = (const float*)d_in[0];
    const float* g1    = (const float*)d_in[1];   // eq_low_gain      (100 Hz)
    const float* g2    = (const float*)d_in[2];   // eq_low_mid_gain  (500 Hz)
    const float* g3    = (const float*)d_in[3];   // eq_high_mid_gain (3 kHz)
    const float* g4    = (const float*)d_in[4];   // eq_high_gain     (10 kHz)
    const float* thr   = (const float*)d_in[5];
    const float* ratio = (const float*)d_in[6];
    const float* att   = (const float*)d_in[7];
    const float* rel   = (const float*)d_in[8];
    const float* mkup  = (const float*)d_in[9];
    const float* sat   = (const float*)d_in[10];

    float* out  = (float*)d_out;          // ping-pong buffer + gs scratch
    float* bufA = (float*)d_ws;           // 2T floats (23.04 MB)
    float* ga   = bufA + 2 * T_LEN;       // 2T floats (total ws use: 46.1 MB)

    eq_band_kernel<<<NBLK_EQ, 256, 0, stream>>>(audio, out,  g1, 100.0f);
    eq_band_kernel<<<NBLK_EQ, 256, 0, stream>>>(out,   bufA, g2, 500.0f);
    eq_band_kernel<<<NBLK_EQ, 256, 0, stream>>>(bufA,  out,  g3, 3000.0f);
    eq_band_kernel<<<NBLK_EQ, 256, 0, stream>>>(out,   bufA, g4, 10000.0f);

    const int nel = 2 * T_LEN;
    gr_kernel<<<(nel + 255) / 256, 256, 0, stream>>>(bufA, ga, thr, ratio, att);
    scan_kernel<<<12, 64, 0, stream>>>(ga, out, att, rel);
    final_kernel<<<(nel + 255) / 256, 256, 0, stream>>>(bufA, out, mkup, sat);
}

// Round 2
// 945.686 us; speedup vs baseline: 1.4928x; 1.4928x over previous
//
#include <hip/hip_runtime.h>
#include <math.h>

// ---------------- problem constants ----------------
#define T_LEN   2880000      // samples per channel
#define LASTFR  5625         // frames t = 0..5625
#define NBLK_EQ 625          // 625 * 9 * 512 = 2,880,000
#define SCAN_B  3840         // scan block size (750 blocks/channel)
#define SCAN_L  30720        // scan warm-up (contraction e^-6.4)
#define SCAN_THREADS 1500

typedef float2 c2;
__device__ __forceinline__ c2 cadd(c2 a, c2 b){ return make_float2(a.x+b.x, a.y+b.y); }
__device__ __forceinline__ c2 csub(c2 a, c2 b){ return make_float2(a.x-b.x, a.y-b.y); }
__device__ __forceinline__ c2 cmul(c2 a, c2 b){ return make_float2(a.x*b.x - a.y*b.y, a.x*b.y + a.y*b.x); }
__device__ __forceinline__ c2 cmulj(c2 a, c2 b){ return make_float2(a.x*b.x + a.y*b.y, a.y*b.x - a.x*b.y); } // a*conj(b)

// 8-point DFT in registers. SGN=-1: forward (W8 = e^{-2pi i/8}); SGN=+1: inverse kernel (unnormalized).
// Verified by hand on delta inputs: x=d1 -> X_m = W8^{SGN*m}.
template<int SGN>
__device__ __forceinline__ void dft8(c2 v[8]) {
    const float r = 0.70710678118654752f;
    c2 t0 = cadd(v[0], v[4]), t1 = csub(v[0], v[4]);
    c2 t2 = cadd(v[2], v[6]), t3 = csub(v[2], v[6]);
    c2 u0 = cadd(v[1], v[5]), u1 = csub(v[1], v[5]);
    c2 u2 = cadd(v[3], v[7]), u3 = csub(v[3], v[7]);
    c2 t3r = (SGN < 0) ? make_float2(t3.y, -t3.x) : make_float2(-t3.y, t3.x);  // (-+i)*t3
    c2 u3r = (SGN < 0) ? make_float2(u3.y, -u3.x) : make_float2(-u3.y, u3.x);
    c2 E0 = cadd(t0, t2), E2 = csub(t0, t2);
    c2 E1 = cadd(t1, t3r), E3 = csub(t1, t3r);
    c2 O0 = cadd(u0, u2), O2 = csub(u0, u2);
    c2 O1 = cadd(u1, u3r), O3 = csub(u1, u3r);
    c2 O1w = (SGN < 0) ? make_float2(r*(O1.x+O1.y), r*(O1.y-O1.x))     // *(r,-r)
                       : make_float2(r*(O1.x-O1.y), r*(O1.x+O1.y));    // *(r, r)
    c2 O2w = (SGN < 0) ? make_float2(O2.y, -O2.x) : make_float2(-O2.y, O2.x); // *(-+i)
    c2 O3w = (SGN < 0) ? make_float2(r*(O3.y-O3.x), -r*(O3.x+O3.y))    // *(-r,-r)
                       : make_float2(-r*(O3.x+O3.y), r*(O3.x-O3.y));   // *(-r, r)
    v[0] = cadd(E0, O0);  v[4] = csub(E0, O0);
    v[1] = cadd(E1, O1w); v[5] = csub(E1, O1w);
    v[2] = cadd(E2, O2w); v[6] = csub(E2, O2w);
    v[3] = cadd(E3, O3w); v[7] = csub(E3, O3w);
}

__device__ __forceinline__ c2 shx(c2 v, int m) {
    return make_float2(__shfl_xor(v.x, m), __shfl_xor(v.y, m));
}

// emit one finished 512-sample chunk (slots r0,r1) with wsum normalization (verified R1)
__device__ __forceinline__ void emit_chunk(float* __restrict__ dst, const float* __restrict__ WN,
                                           int cchunk, int tid, c2 r0, c2 r1) {
    #pragma unroll
    for (int q = 0; q < 2; ++q) {
        c2 rr = (q == 0) ? r0 : r1;
        int m = cchunk * 512 + (q << 8) + tid;
        int tmn = (m >= 2048) ? (((m - 2048) >> 9) + 1) : 0;
        int tmx = min(LASTFR, m >> 9);
        float wsum = 0.0f;
        for (int tt = tmn; tt <= tmx; ++tt) {
            float w = WN[m - (tt << 9)];
            wsum += w * w;
        }
        float inv = (wsum > 1e-11f) ? (1.0f / wsum) : 1.0f;
        int o = m - 1024;
        dst[o]         = rr.x * inv;
        dst[T_LEN + o] = rr.y * inv;
    }
}

// One EQ band: no-reorder fast convolution.
// Forward DIF: radix-8 (s=256), radix-8 (s=32), radix-8 (s=4, in regs), radix-4 (quad shfl).
// Scrambled index map: position holds X[k], k = m1 + 8*m2 + 64*m3 + 512*bitrev2(j).
// Mask (real, even, /2048 folded) precomputed in scrambled layout MKs[m*256+tid].
// Inverse: transposed-conjugate stages in reverse order; output lands at {tid+256k} = OLA ring slots.
__global__ __launch_bounds__(256) void eq_band_kernel(
    const float* __restrict__ src, float* __restrict__ dst,
    const float* __restrict__ gain_db_p, const float f0)
{
    __shared__ c2 SA[2048];      // 16 KB work buffer (in-place)
    __shared__ c2 TWs1[2048];    // 16 KB  W_2048^{j*m}, m-major
    __shared__ c2 TWs2[256];     //  2 KB  W_256^{j2*m}, m-major
    __shared__ c2 TWs3[32];      //  256 B W_32^{j*m}, m-major
    __shared__ float MKs[2048];  //  8 KB  scrambled mask * (1/2048)
    __shared__ float WN[2048];   //  8 KB  hann
    // total ~50.5 KB -> 3 blocks/CU

    const int tid = threadIdx.x;
    const int b   = blockIdx.x;

    const float gdb   = *gain_db_p;
    const float g_lin = exp2f(gdb * 0.16609640474436813f);  // 10^(g/20)
    const float gm1   = g_lin - 1.0f;

    const float st2048 = 6.283185307179586f / 2048.0f;
    for (int idx = tid; idx < 2048; idx += 256) {
        int m = idx >> 8, j = idx & 255;
        float ang = st2048 * (float)(j * m);
        TWs1[idx] = make_float2(cosf(ang), -sinf(ang));
        WN[idx] = 0.5f - 0.5f * cosf(st2048 * (float)idx);
        // scrambled mask: for (m3=m, thread tt): k = (b>>3) + 8*(b&7) + 64*m3 + 512*bitrev2(j)
        int tt = idx & 255;
        int bb = tt >> 2, jj = tt & 3;
        int qrev = ((jj & 1) << 1) | (jj >> 1);
        int k = (bb >> 3) + ((bb & 7) << 3) + (m << 6) + (qrev << 9);
        int kk = (k > 1024) ? (2048 - k) : k;
        float f = (float)kk * (24000.0f / 1024.0f);
        float d = (f - f0) / f0;                 // q = 1
        MKs[idx] = (1.0f + gm1 * expf(-d * d)) * (1.0f / 2048.0f);
    }
    {
        int m = tid >> 5, j2 = tid & 31;
        float ang = (6.283185307179586f / 256.0f) * (float)(j2 * m);
        TWs2[tid] = make_float2(cosf(ang), -sinf(ang));
    }
    if (tid < 32) {
        int m = tid >> 2, j = tid & 3;
        float ang = (6.283185307179586f / 32.0f) * (float)(j * m);
        TWs3[tid] = make_float2(cosf(ang), -sinf(ang));
    }
    __syncthreads();

    const int t0   = max(0, 9 * b - 1);
    const int t1   = min(LASTFR, 9 * b + 10);
    const int cmin = 9 * b + 2;
    const int cmax = 9 * b + 10;

    c2 ring[8];
    #pragma unroll
    for (int q = 0; q < 8; ++q) ring[q] = make_float2(0.0f, 0.0f);

    for (int t = t0; t <= t1; ++t) {
        // load + window (reflect pad folded); both channels packed ch0 + i*ch1
        for (int j = tid; j < 2048; j += 256) {
            int ss = t * 512 + j - 1024;
            ss = (ss < 0) ? -ss : ss;
            ss = (ss >= T_LEN) ? (2 * T_LEN - 2 - ss) : ss;
            float w = WN[j];
            SA[j] = make_float2(src[ss] * w, src[T_LEN + ss] * w);
        }
        __syncthreads();

        c2 v[8];

        // F1: radix-8, s=256, groups {tid+256k}, in-place (own set only)
        #pragma unroll
        for (int k = 0; k < 8; ++k) v[k] = SA[tid + (k << 8)];
        dft8<-1>(v);
        #pragma unroll
        for (int m = 1; m < 8; ++m) v[m] = cmul(v[m], TWs1[(m << 8) + tid]);
        #pragma unroll
        for (int m = 0; m < 8; ++m) SA[tid + (m << 8)] = v[m];
        __syncthreads();

        // F2: radix-8, s=32 within 256-blocks; write with XOR-4 swizzle (bank-free, needs mid-sync)
        {
            int c = tid >> 5, j2 = tid & 31;
            int base = (c << 8) + j2;
            #pragma unroll
            for (int k = 0; k < 8; ++k) v[k] = SA[base + (k << 5)];
            dft8<-1>(v);
            #pragma unroll
            for (int m = 1; m < 8; ++m) v[m] = cmul(v[m], TWs2[(m << 5) + j2]);
            __syncthreads();
            #pragma unroll
            for (int m = 0; m < 8; ++m) SA[(c << 8) + (m << 5) + (j2 ^ (m << 2))] = v[m];
        }
        __syncthreads();

        // F3 (radix-8, s=4, in regs) + F4 (quad DFT4) + mask + I1 (quad inv) + I2 (conj(S3^T))
        {
            int bb = tid >> 2, j = tid & 3;
            int base = bb << 5, bx = (bb & 7) << 2;
            #pragma unroll
            for (int k = 0; k < 8; ++k) v[k] = SA[base + ((k << 2) ^ bx) + j];
            dft8<-1>(v);
            #pragma unroll
            for (int m = 1; m < 8; ++m) v[m] = cmul(v[m], TWs3[(m << 2) + j]);
            #pragma unroll
            for (int m = 0; m < 8; ++m) {
                // F4: distributed DFT4 over quad lanes j; output lane order [X0,X2,X1,X3]
                c2 w = v[m];
                c2 p = shx(w, 2);
                c2 e  = (j & 2) ? csub(p, w) : cadd(w, p);
                c2 qq = shx(e, 1);
                c2 lo = (j & 1) ? csub(qq, e) : cadd(e, qq);
                c2 hi = (j & 1) ? make_float2(qq.x - e.y, qq.y + e.x)   // qq + i*e
                                : make_float2(e.x + qq.y, e.y - qq.x);  // e - i*qq
                w = (j & 2) ? hi : lo;
                // mask in scrambled order
                float mk = MKs[(m << 8) + tid];
                w.x *= mk; w.y *= mk;
                // I1: inverse quad (consumes [X0,X2,X1,X3], yields natural y_j)
                c2 p2 = shx(w, 1);
                c2 e2 = (j & 1) ? csub(p2, w) : cadd(w, p2);
                c2 q2 = shx(e2, 2);
                c2 lo2 = (j & 1) ? make_float2(e2.x - q2.y, e2.y + q2.x)  // e2 + i*q2
                                 : cadd(e2, q2);
                c2 hi2 = (j & 1) ? make_float2(q2.x + e2.y, q2.y - e2.x)  // q2 - i*e2
                                 : csub(q2, e2);
                v[m] = (j & 2) ? hi2 : lo2;
            }
            // I2: pre-twiddle conj(W_32^{jm}), inverse dft8, write swizzled (same set as F3 reads)
            #pragma unroll
            for (int m = 1; m < 8; ++m) v[m] = cmulj(v[m], TWs3[(m << 2) + j]);
            dft8<+1>(v);
            __syncthreads();   // all F3 reads complete before overwrite
            #pragma unroll
            for (int k = 0; k < 8; ++k) SA[base + ((k << 2) ^ bx) + j] = v[k];
        }
        __syncthreads();

        // I3: conj(S2^T): read swizzled, pre-twiddle conj(W_256), inv dft8, write natural
        {
            int c = tid >> 5, j2 = tid & 31;
            #pragma unroll
            for (int m = 0; m < 8; ++m) v[m] = SA[(c << 8) + (m << 5) + (j2 ^ (m << 2))];
            #pragma unroll
            for (int m = 1; m < 8; ++m) v[m] = cmulj(v[m], TWs2[(m << 5) + j2]);
            dft8<+1>(v);
            __syncthreads();
            #pragma unroll
            for (int k = 0; k < 8; ++k) SA[(c << 8) + (k << 5) + j2] = v[k];
        }
        __syncthreads();

        // I4: conj(S1^T): time samples at {tid+256k} -> synthesis window -> OLA ring (no LDS write)
        {
            #pragma unroll
            for (int m = 0; m < 8; ++m) v[m] = SA[tid + (m << 8)];
            #pragma unroll
            for (int m = 1; m < 8; ++m) v[m] = cmulj(v[m], TWs1[(m << 8) + tid]);
            dft8<+1>(v);
            #pragma unroll
            for (int k = 0; k < 8; ++k) {
                float w = WN[tid + (k << 8)];
                ring[k].x += v[k].x * w;   // ch0 = Re, ch1 = Im (true IDFT, mask real)
                ring[k].y += v[k].y * w;
            }
        }
        __syncthreads();   // I4 reads done before next frame's window write

        if (t >= cmin) emit_chunk(dst, WN, t, tid, ring[0], ring[1]);
        #pragma unroll
        for (int q = 0; q < 6; ++q) ring[q] = ring[q + 2];
        ring[6] = make_float2(0.0f, 0.0f);
        ring[7] = make_float2(0.0f, 0.0f);
    }
    // tail (last block only)
    for (int c = t1 + 1; c <= cmax; ++c) {
        emit_chunk(dst, WN, c, tid, ring[0], ring[1]);
        #pragma unroll
        for (int q = 0; q < 6; ++q) ring[q] = ring[q + 2];
        ring[6] = make_float2(0.0f, 0.0f);
        ring[7] = make_float2(0.0f, 0.0f);
    }
}

// per-sample gain-reduction * a_att (gr[0] of each channel zeroed => exact i=0 boundary)
__global__ __launch_bounds__(256) void gr_kernel(
    const float* __restrict__ y, float* __restrict__ ga,
    const float* __restrict__ thr_p, const float* __restrict__ ratio_p,
    const float* __restrict__ att_p)
{
    int i = blockIdx.x * 256 + threadIdx.x;
    if (i >= 2 * T_LEN) return;
    float thr   = *thr_p;
    float ratio = *ratio_p;
    float a_att = 1.0f - expf(-1.0f / ((*att_p) * 48000.0f));
    float v  = y[i];
    float aa = fabsf(v) + 1e-8f;
    float adb = 6.020599913279624f * __log2f(aa);
    float gr  = fmaxf(adb - thr, 0.0f) * (1.0f - 1.0f / ratio);
    float gav = gr * a_att;
    if (i == 0 || i == T_LEN) gav = 0.0f;
    ga[i] = gav;
}

// one scan-proc: 16 sequential IIR updates + prefetch 128 samples ahead
__device__ __forceinline__ void scan_proc(const float* __restrict__ g, float* __restrict__ out,
                                          float4 (&row)[4], int& i, float& prev,
                                          float A, float B, float ra, bool store)
{
    float4 a0 = row[0], a1 = row[1], a2 = row[2], a3 = row[3];
    int pf = i + 128;
    pf = (pf > T_LEN - 16) ? (T_LEN - 16) : pf;
    row[0] = *(const float4*)(g + pf);
    row[1] = *(const float4*)(g + pf + 4);
    row[2] = *(const float4*)(g + pf + 8);
    row[3] = *(const float4*)(g + pf + 12);
    float v[16] = {a0.x, a0.y, a0.z, a0.w, a1.x, a1.y, a1.z, a1.w,
                   a2.x, a2.y, a2.z, a2.w, a3.x, a3.y, a3.z, a3.w};
    float ov[16];
    #pragma unroll
    for (int k = 0; k < 16; ++k) {
        // new = max((1-a_att)p + a_att*g, (1-a_rel)p + a_rel*g)  == reference step
        prev = fmaxf(fmaf(A, prev, v[k]), fmaf(B, prev, v[k] * ra));
        ov[k] = prev;
    }
    if (store) {
        *(float4*)(out + i)      = make_float4(ov[0], ov[1], ov[2], ov[3]);
        *(float4*)(out + i + 4)  = make_float4(ov[4], ov[5], ov[6], ov[7]);
        *(float4*)(out + i + 8)  = make_float4(ov[8], ov[9], ov[10], ov[11]);
        *(float4*)(out + i + 12) = make_float4(ov[12], ov[13], ov[14], ov[15]);
    }
    i += 16;
}

// block-parallel IIR gain smoothing with warm-up.
// __launch_bounds__(64, 1): 512-VGPR budget so the 8x4 float4 prefetch ring stays in registers
// (R1: 136 VGPRs => ring spilled to scratch => 33 cyc/step instead of ~10).
__global__ __launch_bounds__(64, 1) void scan_kernel(
    const float* __restrict__ ga, float* __restrict__ gs,
    const float* __restrict__ att_p, const float* __restrict__ rel_p)
{
    int gid = blockIdx.x * 64 + threadIdx.x;
    if (gid >= SCAN_THREADS) return;               // 750 blocks x 2 channels
    int c   = gid / 750;
    int blk = gid - c * 750;
    const float* __restrict__ g  = ga + c * T_LEN;
    float* __restrict__ out      = gs + c * T_LEN;

    float A  = expf(-1.0f / ((*att_p) * 48000.0f));   // 1 - a_att
    float B  = expf(-1.0f / ((*rel_p) * 48000.0f));   // 1 - a_rel
    float ra = (1.0f - B) / (1.0f - A);               // a_rel / a_att

    int o0     = blk * SCAN_B;
    int wstart = max(0, o0 - SCAN_L);
    int warm_groups = (o0 - wstart) >> 7;             // 128 samples per group

    float4 rb[8][4];                                  // 128-sample prefetch ring
    #pragma unroll
    for (int l = 0; l < 8; ++l) {
        int idx = wstart + (l << 4);
        #pragma unroll
        for (int q = 0; q < 4; ++q)
            rb[l][q] = *(const float4*)(g + idx + (q << 2));
    }
    float prev = 0.0f;
    int i = wstart;

    for (int grp = 0; grp < warm_groups; ++grp) {
        #pragma unroll
        for (int ph = 0; ph < 8; ++ph)
            scan_proc(g, out, rb[ph], i, prev, A, B, ra, false);
    }
    for (int grp = 0; grp < SCAN_B / 128; ++grp) {    // 30*128 = 3840 outputs
        #pragma unroll
        for (int ph = 0; ph < 8; ++ph)
            scan_proc(g, out, rb[ph], i, prev, A, B, ra, true);
    }
}

// makeup/gain application + saturation; gs read from io and overwritten in place
__global__ __launch_bounds__(256) void final_kernel(
    const float* __restrict__ y, float* __restrict__ io,
    const float* __restrict__ mk_p, const float* __restrict__ sat_p)
{
    int i = blockIdx.x * 256 + threadIdx.x;
    if (i >= 2 * T_LEN) return;
    float mk  = *mk_p;
    float sat = *sat_p;
    float v   = y[i];
    float gsv = io[i];
    float aa  = fabsf(v) + 1e-8f;
    float gl  = exp2f((mk - gsv) * 0.16609640474436813f);  // 10^((mk-gs)/20)
    float r   = aa * gl;
    r = (v < 0.0f) ? -r : r;
    if (sat > 1.0f) r = tanhf(r * sat) / sat;
    io[i] = r;
}

extern "C" void kernel_launch(void* const* d_in, const int* in_sizes, int n_in,
                              void* d_out, int out_size, void* d_ws, size_t ws_size,
                              hipStream_t stream)
{
    const float* audio = (const float*)d_in[0];
    const float* g1    = (const float*)d_in[1];   // eq_low_gain      (100 Hz)
    const float* g2    = (const float*)d_in[2];   // eq_low_mid_gain  (500 Hz)
    const float* g3    = (const float*)d_in[3];   // eq_high_mid_gain (3 kHz)
    const float* g4    = (const float*)d_in[4];   // eq_high_gain     (10 kHz)
    const float* thr   = (const float*)d_in[5];
    const float* ratio = (const float*)d_in[6];
    const float* att   = (const float*)d_in[7];
    const float* rel   = (const float*)d_in[8];
    const float* mkup  = (const float*)d_in[9];
    const float* sat   = (const float*)d_in[10];

    float* out  = (float*)d_out;          // ping-pong buffer + gs scratch
    float* bufA = (float*)d_ws;           // 2T floats (23.04 MB)
    float* ga   = bufA + 2 * T_LEN;       // 2T floats (total ws use: 46.1 MB)

    eq_band_kernel<<<NBLK_EQ, 256, 0, stream>>>(audio, out,  g1, 100.0f);
    eq_band_kernel<<<NBLK_EQ, 256, 0, stream>>>(out,   bufA, g2, 500.0f);
    eq_band_kernel<<<NBLK_EQ, 256, 0, stream>>>(bufA,  out,  g3, 3000.0f);
    eq_band_kernel<<<NBLK_EQ, 256, 0, stream>>>(out,   bufA, g4, 10000.0f);

    const int nel = 2 * T_LEN;
    gr_kernel<<<(nel + 255) / 256, 256, 0, stream>>>(bufA, ga, thr, ratio, att);
    scan_kernel<<<(SCAN_THREADS + 63) / 64, 64, 0, stream>>>(ga, out, att, rel);
    final_kernel<<<(nel + 255) / 256, 256, 0, stream>>>(bufA, out, mkup, sat);
}